// Round 16
// baseline (536.468 us; speedup 1.0000x reference)
//
#include <hip/hip_runtime.h>
#include <hip/hip_bf16.h>
#include <stdint.h>

// Problem constants
#define S_LEN 2048
#define BATCH 32
#define MROWS (S_LEN*BATCH)   // 65536 GEMM rows, K=N=1024

typedef __attribute__((ext_vector_type(8))) short bf16x8;
typedef __attribute__((ext_vector_type(4))) float f32x4;
typedef unsigned short ushort_t;

__device__ inline unsigned int pk2bf(float a, float b) {
  float2 t; t.x = a; t.y = b;
  __hip_bfloat162 h = __float22bfloat162_rn(t);
  union { __hip_bfloat162 h; unsigned int u; } c; c.h = h;
  return c.u;
}

__device__ inline float bflo(unsigned int u) { return __uint_as_float(u << 16); }
__device__ inline float bfhi(unsigned int u) { return __uint_as_float(u & 0xffff0000u); }

__device__ inline void gload_lds16(const void* g, void* l) {
  __builtin_amdgcn_global_load_lds(
      (const __attribute__((address_space(1))) unsigned int*)g,
      (__attribute__((address_space(3))) unsigned int*)l, 16, 0, 0);
}

__device__ inline float fast_tanh(float x) {
  float e = __expf(2.0f * x);
  return 1.0f - 2.0f / (e + 1.0f);
}

// ---------------------------------------------------------------------------
// prep_small: blocks 0..63 convert Wc -> bf16;
//             blocks 64..95 compute wsum[b][n] = sum_d dec[b][d]*Wb[n][d]
// ---------------------------------------------------------------------------
__global__ __launch_bounds__(256) void prep_small_kernel(
    const float* __restrict__ dec, const float* __restrict__ Wb,
    const float* __restrict__ Wc, ushort_t* __restrict__ WcBf,
    float* __restrict__ wsum)
{
  const int t = threadIdx.x;
  const int bid = blockIdx.x;
  if (bid < 64) {
    const int base = bid * 16384;
    for (int i = 0; i < 16; ++i) {
      int idx = base + i * 1024 + t * 4;
      float4 v = *(const float4*)(Wc + idx);
      uint2 w; w.x = pk2bf(v.x, v.y); w.y = pk2bf(v.z, v.w);
      *(uint2*)(WcBf + idx) = w;
    }
  } else {
    const int j = bid - 64;                     // n-slice [j*32, j*32+32)
    __shared__ float sdec[32][65];
    __shared__ float swb[32][65];
    const int b = t & 31, nl = t >> 5;
    float acc0 = 0.f, acc1 = 0.f, acc2 = 0.f, acc3 = 0.f;
    for (int c = 0; c < 16; ++c) {
      __syncthreads();
      for (int idx = t; idx < 2048; idx += 256) {
        int rr = idx >> 6, dd = idx & 63;
        sdec[rr][dd] = dec[rr * 1024 + c * 64 + dd];
        swb[rr][dd]  = Wb[(size_t)(j * 32 + rr) * 1024 + c * 64 + dd];
      }
      __syncthreads();
      #pragma unroll 8
      for (int dd = 0; dd < 64; ++dd) {
        float dv = sdec[b][dd];
        acc0 += dv * swb[nl][dd];
        acc1 += dv * swb[nl + 8][dd];
        acc2 += dv * swb[nl + 16][dd];
        acc3 += dv * swb[nl + 24][dd];
      }
    }
    wsum[b * 1024 + j * 32 + nl]      = acc0;
    wsum[b * 1024 + j * 32 + nl + 8]  = acc1;
    wsum[b * 1024 + j * 32 + nl + 16] = acc2;
    wsum[b * 1024 + j * 32 + nl + 24] = acc3;
  }
}

// ---------------------------------------------------------------------------
// score (fused m97 structure + fence-free A register prefetch): BM=128,
// BN=128, BK=64, 4 waves (2x2), wave 64x64, single-buffered 32KB LDS,
// 2 x __syncthreads per K-step, 4 blocks/CU.
// Per K-step: convert av(kt)->ds_write A ; B DMA ; sync ; ISSUE av(kt+1)
// register loads INSIDE the MFMA phase (closing __syncthreads' vmcnt(0)
// drain guarantees completion — no raw barriers, no counted vmcnt, no
// sched_barrier: correctness is structural). A's L2 latency hides under
// the ~300cy MFMA phase instead of stalling the convert.
// nblk==0 blocks persist the bf16 A tile to encBf for ctx.
// XOR-8 chunk swizzle on both operands -> conflict-free frag reads.
// XCD-aware bid decode: 8 blocks sharing an A-panel -> same XCD L2.
// Epilogue: scoreP8T[b][s][nblk] = sum_col tanh(acc + wsum) * Wa.
// ---------------------------------------------------------------------------
__global__ __launch_bounds__(256, 4) void score_kernel(
    const float4* __restrict__ encF4, ushort_t* __restrict__ encBf,
    const ushort_t* __restrict__ WcBf, const float* __restrict__ wsum,
    const float* __restrict__ Wa, float* __restrict__ scoreP8T)
{
  __shared__ ushort_t Ab[128][64];   // 16 KB
  __shared__ ushort_t Bb[128][64];   // 16 KB
  __shared__ float scorep[128];

  const int tid = threadIdx.x;
  const int lane = tid & 63;
  const int l15 = lane & 15, q = lane >> 4;
  const int r7 = l15 & 7;
  const int wid = tid >> 6;
  const int wr = wid >> 1, wc = wid & 1;        // 2M x 2N waves
  const int bid = blockIdx.x;
  const int mi = bid & 15, nblk = (bid >> 4) & 7, mg = bid >> 7;
  const size_t rowBase = (size_t)(mg * 16 + mi) * 128;

  if (tid < 128) scorep[tid] = 0.f;

  // A staging (slot map, fully coalesced): row = k*16 + (tid>>4), f4 = tid&15
  const int tRow = tid >> 4;                    // 0..15
  const int f4 = tid & 15;
  const int swzT = (((f4 >> 1) ^ (tRow & 7)) * 8) + ((f4 & 1) * 4); // ushort units
  const float4* aTB = encF4 + (rowBase + tRow) * 256 + f4;  // +k*4096, +kt*16

  // B staging: 1024 slots of 16B, 4 per thread, gload_lds w/ pre-swz source
  int bOff[4], dOff[4];
  #pragma unroll
  for (int k = 0; k < 4; ++k) {
    const int s = k * 256 + tid;
    const int r = s >> 3, c = s & 7;
    bOff[k] = (int)((nblk * 128 + r) * 1024 + ((c ^ (r & 7)) * 8));
    dOff[k] = s * 8;
  }
  ushort_t* const aL = &Ab[0][0];
  ushort_t* const bL = &Bb[0][0];

  int aRow[4], bRow[4];
  #pragma unroll
  for (int m = 0; m < 4; ++m) aRow[m] = (wr * 64 + m * 16 + l15) * 64;
  #pragma unroll
  for (int n = 0; n < 4; ++n) bRow[n] = (wc * 64 + n * 16 + l15) * 64;
  const int ch0 = (q ^ r7) * 8;
  const int ch1 = ((4 + q) ^ r7) * 8;

  f32x4 acc[4][4];
  #pragma unroll
  for (int m = 0; m < 4; ++m)
    #pragma unroll
    for (int n = 0; n < 4; ++n) { f32x4 z = {0.f,0.f,0.f,0.f}; acc[m][n] = z; }

  // prologue: A(kt=0) into registers
  float4 av[8];
  #pragma unroll
  for (int k = 0; k < 8; ++k) av[k] = aTB[k * 4096];

  for (int kt = 0; kt < 16; ++kt) {
    const int ko = kt * 64;
    // B: async LDS-DMA (safe: all waves passed the closing barrier)
    #pragma unroll
    for (int k = 0; k < 4; ++k)
      gload_lds16(WcBf + ko + bOff[k], bL + dOff[k]);

    // A: convert prefetched regs -> swizzled LDS write (+ persist if nblk==0)
    #pragma unroll
    for (int k = 0; k < 8; ++k) {
      uint2 w;
      w.x = pk2bf(av[k].x, av[k].y);
      w.y = pk2bf(av[k].z, av[k].w);
      const int r = k * 16 + tRow;
      *(uint2*)(aL + r * 64 + swzT) = w;
      if (nblk == 0)
        *(uint2*)(encBf + (rowBase + r) * 1024 + ko + f4 * 4) = w;
    }
    __syncthreads();   // drains B DMA + A ds_writes: both tiles ready

    // fence-free A prefetch: register loads issued inside the MFMA phase;
    // the closing __syncthreads (vmcnt(0) + fence) guarantees completion.
    if (kt < 15) {
      #pragma unroll
      for (int k = 0; k < 8; ++k) av[k] = aTB[k * 4096 + (kt + 1) * 16];
    }

    #pragma unroll
    for (int kk = 0; kk < 2; ++kk) {
      const int cho = kk ? ch1 : ch0;
      bf16x8 af[4], bv[4];
      #pragma unroll
      for (int m = 0; m < 4; ++m) af[m] = *(const bf16x8*)(aL + aRow[m] + cho);
      #pragma unroll
      for (int n = 0; n < 4; ++n) bv[n] = *(const bf16x8*)(bL + bRow[n] + cho);
      #pragma unroll
      for (int m = 0; m < 4; ++m)
        #pragma unroll
        for (int n = 0; n < 4; ++n)
          acc[m][n] = __builtin_amdgcn_mfma_f32_16x16x32_bf16(
              af[m], bv[n], acc[m][n], 0, 0, 0);
    }
    __syncthreads();   // compute done + prefetch drained before next iter
  }

  #pragma unroll
  for (int m = 0; m < 4; ++m) {
    #pragma unroll
    for (int i = 0; i < 4; ++i) {
      const int rowl = wr * 64 + m * 16 + q * 4 + i;
      const int bb2 = rowl & 31;                // global row %32 == rowl%32
      float v = 0.f;
      #pragma unroll
      for (int n = 0; n < 4; ++n) {
        const int col = nblk * 128 + wc * 64 + n * 16 + l15;
        float x = acc[m][n][i] + wsum[bb2 * 1024 + col];
        v += fast_tanh(x) * Wa[col];
      }
      v += __shfl_xor(v, 1); v += __shfl_xor(v, 2);
      v += __shfl_xor(v, 4); v += __shfl_xor(v, 8);
      if (l15 == 0) atomicAdd(&scorep[rowl], v);
    }
  }
  __syncthreads();
  if (tid < 128) {
    const int grow = (int)rowBase + tid;
    const int b = grow & 31, s = grow >> 5;
    scoreP8T[((b * 2048 + s) << 3) + nblk] = scorep[tid];
  }
}

// ---------------------------------------------------------------------------
// ctx_partial (deterministic, NO global atomics): block (b, sc).
// Exp only for own 64 s (normalization deferred); wave-reduce chunk exp-sum
// -> gSum[sc*32+b]; accumulate partial[sc][b][e] with plain float4 stores.
// ---------------------------------------------------------------------------
__global__ __launch_bounds__(256) void ctx_partial_kernel(
    const ushort_t* __restrict__ encBf, const float* __restrict__ scoreP8T,
    float* __restrict__ partial, float* __restrict__ gSum)
{
  const int b = blockIdx.x & 31, sc = blockIdx.x >> 5;
  const int t = threadIdx.x;
  __shared__ float eCh[64];

  const int chunk0 = sc * 64;
  if (t < 64) {
    const float4* p = (const float4*)(scoreP8T +
                        (((size_t)b * 2048 + chunk0 + t) << 3));
    float4 u = p[0], v = p[1];
    float scv = ((u.x + u.y) + (u.z + u.w)) + ((v.x + v.y) + (v.z + v.w));
    float e = __expf(scv);                      // scores O(1): no max needed
    eCh[t] = e;
    float sum = e;
    sum += __shfl_xor(sum, 1);  sum += __shfl_xor(sum, 2);
    sum += __shfl_xor(sum, 4);  sum += __shfl_xor(sum, 8);
    sum += __shfl_xor(sum, 16); sum += __shfl_xor(sum, 32);
    if (t == 0) gSum[sc * 32 + b] = sum;
  }
  __syncthreads();

  float a0 = 0.f, a1 = 0.f, a2 = 0.f, a3 = 0.f;
  const int e0 = t * 4;
  #pragma unroll 4
  for (int si = 0; si < 64; ++si) {
    const int s = chunk0 + si;
    const float a = eCh[si];
    uint2 w = *(const uint2*)(encBf + ((size_t)s * 32 + b) * 1024 + e0);
    a0 += a * bflo(w.x); a1 += a * bfhi(w.x);
    a2 += a * bflo(w.y); a3 += a * bfhi(w.y);
  }
  *(float4*)(partial + ((size_t)(sc * 32 + b)) * 1024 + e0) =
      make_float4(a0, a1, a2, a3);
}

// ---------------------------------------------------------------------------
// ctx_reduce: block b. Sum 32 chunk partials + 32 chunk exp-sums, scale by
// 1/total, write out directly (no pre-zeroing needed anywhere).
// ---------------------------------------------------------------------------
__global__ __launch_bounds__(256) void ctx_reduce_kernel(
    const float* __restrict__ partial, const float* __restrict__ gSum,
    float* __restrict__ out)
{
  const int b = blockIdx.x, t = threadIdx.x;
  float tot = 0.f;
  #pragma unroll
  for (int sc = 0; sc < 32; ++sc) tot += gSum[sc * 32 + b];
  const float inv = 1.0f / tot;

  float4 acc = make_float4(0.f, 0.f, 0.f, 0.f);
  #pragma unroll
  for (int sc = 0; sc < 32; ++sc) {
    float4 v = *(const float4*)(partial + ((size_t)(sc * 32 + b)) * 1024 + t * 4);
    acc.x += v.x; acc.y += v.y; acc.z += v.z; acc.w += v.w;
  }
  acc.x *= inv; acc.y *= inv; acc.z *= inv; acc.w *= inv;
  *(float4*)(out + (size_t)b * 1024 + t * 4) = acc;
}

// ---------------------------------------------------------------------------
extern "C" void kernel_launch(void* const* d_in, const int* in_sizes, int n_in,
                              void* d_out, int out_size, void* d_ws, size_t ws_size,
                              hipStream_t stream) {
  const float* dec = (const float*)d_in[0];
  const float* enc = (const float*)d_in[1];
  const float* Wb  = (const float*)d_in[2];
  const float* Wc  = (const float*)d_in[3];
  const float* Wa  = (const float*)d_in[4];
  float* out = (float*)d_out;
  (void)in_sizes; (void)n_in; (void)ws_size; (void)out_size;

  char* ws = (char*)d_ws;
  ushort_t* encBf    = (ushort_t*)ws;                                    // 128 MB
  ushort_t* WcBf     = (ushort_t*)(ws + 134217728);                      // 2 MB
  float*    wsum     = (float*)(ws + 134217728 + 2097152);               // 128 KB
  float*    scoreP8T = (float*)(ws + 134217728 + 2097152 + 131072);      // 2 MB
  float*    partial  = (float*)(ws + 134217728 + 2097152 + 131072 + 2097152);        // 4 MB
  float*    gSum     = (float*)(ws + 134217728 + 2097152 + 131072 + 2097152 + 4194304); // 4 KB

  prep_small_kernel<<<96, 256, 0, stream>>>(dec, Wb, Wc, WcBf, wsum);
  score_kernel<<<4096, 256, 0, stream>>>((const float4*)enc, encBf, WcBf,
                                         wsum, Wa, scoreP8T);
  ctx_partial_kernel<<<1024, 256, 0, stream>>>(encBf, scoreP8T, partial, gSum);
  ctx_reduce_kernel<<<32, 256, 0, stream>>>(partial, gSum, out);
}

// Round 17
// 399.131 us; speedup vs baseline: 1.3441x; 1.3441x over previous
//
#include <hip/hip_runtime.h>
#include <hip/hip_bf16.h>
#include <stdint.h>

// Problem constants
#define S_LEN 2048
#define BATCH 32
#define MROWS (S_LEN*BATCH)   // 65536 GEMM rows, K=N=1024

typedef __attribute__((ext_vector_type(8))) short bf16x8;
typedef __attribute__((ext_vector_type(4))) float f32x4;
typedef unsigned short ushort_t;

__device__ inline unsigned int pk2bf(float a, float b) {
  float2 t; t.x = a; t.y = b;
  __hip_bfloat162 h = __float22bfloat162_rn(t);
  union { __hip_bfloat162 h; unsigned int u; } c; c.h = h;
  return c.u;
}

__device__ inline float bflo(unsigned int u) { return __uint_as_float(u << 16); }
__device__ inline float bfhi(unsigned int u) { return __uint_as_float(u & 0xffff0000u); }

__device__ inline void gload_lds16(const void* g, void* l) {
  __builtin_amdgcn_global_load_lds(
      (const __attribute__((address_space(1))) unsigned int*)g,
      (__attribute__((address_space(3))) unsigned int*)l, 16, 0, 0);
}

__device__ inline float fast_tanh(float x) {
  float e = __expf(2.0f * x);
  return 1.0f - 2.0f / (e + 1.0f);
}

// ---------------------------------------------------------------------------
// prep_small: blocks 0..63 convert Wc -> bf16 (block 0 also zeroes the 32
//             ctx arrival counters — re-zeroed every launch, graph-safe);
//             blocks 64..95 compute wsum[b][n] = sum_d dec[b][d]*Wb[n][d]
// ---------------------------------------------------------------------------
__global__ __launch_bounds__(256) void prep_small_kernel(
    const float* __restrict__ dec, const float* __restrict__ Wb,
    const float* __restrict__ Wc, ushort_t* __restrict__ WcBf,
    float* __restrict__ wsum, unsigned int* __restrict__ counters)
{
  const int t = threadIdx.x;
  const int bid = blockIdx.x;
  if (bid < 64) {
    if (bid == 0 && t < 32) counters[t] = 0u;
    const int base = bid * 16384;
    for (int i = 0; i < 16; ++i) {
      int idx = base + i * 1024 + t * 4;
      float4 v = *(const float4*)(Wc + idx);
      uint2 w; w.x = pk2bf(v.x, v.y); w.y = pk2bf(v.z, v.w);
      *(uint2*)(WcBf + idx) = w;
    }
  } else {
    const int j = bid - 64;                     // n-slice [j*32, j*32+32)
    __shared__ float sdec[32][65];
    __shared__ float swb[32][65];
    const int b = t & 31, nl = t >> 5;
    float acc0 = 0.f, acc1 = 0.f, acc2 = 0.f, acc3 = 0.f;
    for (int c = 0; c < 16; ++c) {
      __syncthreads();
      for (int idx = t; idx < 2048; idx += 256) {
        int rr = idx >> 6, dd = idx & 63;
        sdec[rr][dd] = dec[rr * 1024 + c * 64 + dd];
        swb[rr][dd]  = Wb[(size_t)(j * 32 + rr) * 1024 + c * 64 + dd];
      }
      __syncthreads();
      #pragma unroll 8
      for (int dd = 0; dd < 64; ++dd) {
        float dv = sdec[b][dd];
        acc0 += dv * swb[nl][dd];
        acc1 += dv * swb[nl + 8][dd];
        acc2 += dv * swb[nl + 16][dd];
        acc3 += dv * swb[nl + 24][dd];
      }
    }
    wsum[b * 1024 + j * 32 + nl]      = acc0;
    wsum[b * 1024 + j * 32 + nl + 8]  = acc1;
    wsum[b * 1024 + j * 32 + nl + 16] = acc2;
    wsum[b * 1024 + j * 32 + nl + 24] = acc3;
  }
}

// ---------------------------------------------------------------------------
// score (R15-proven fused m97 structure, byte-identical): BM=128, BN=128,
// BK=64, 4 waves (2x2), wave 64x64. Single-buffered 32KB LDS, 2 barriers per
// K-step, 32 MFMA between barriers; latency hidden by 4 blocks/CU TLP (m114).
// Sync A loads at loop top (register prefetch across MFMA spills — R16).
// A: fp32 enc -> regs -> bf16 -> swizzled ds_write (conversion fused);
//    nblk==0 blocks also persist the bf16 tile to encBf for ctx.
// B: bf16 WcBf via async gload_lds w/ pre-swizzled source.
// XOR-8 chunk swizzle on both operands -> conflict-free frag reads.
// XCD-aware bid decode: 8 blocks sharing an A-panel -> same XCD L2.
// Epilogue: scoreP8T[b][s][nblk] = sum_col tanh(acc + wsum) * Wa.
// ---------------------------------------------------------------------------
__global__ __launch_bounds__(256, 4) void score_kernel(
    const float4* __restrict__ encF4, ushort_t* __restrict__ encBf,
    const ushort_t* __restrict__ WcBf, const float* __restrict__ wsum,
    const float* __restrict__ Wa, float* __restrict__ scoreP8T)
{
  __shared__ ushort_t Ab[128][64];   // 16 KB
  __shared__ ushort_t Bb[128][64];   // 16 KB
  __shared__ float scorep[128];

  const int tid = threadIdx.x;
  const int lane = tid & 63;
  const int l15 = lane & 15, q = lane >> 4;
  const int r7 = l15 & 7;
  const int wid = tid >> 6;
  const int wr = wid >> 1, wc = wid & 1;        // 2M x 2N waves
  const int bid = blockIdx.x;
  const int mi = bid & 15, nblk = (bid >> 4) & 7, mg = bid >> 7;
  const size_t rowBase = (size_t)(mg * 16 + mi) * 128;

  if (tid < 128) scorep[tid] = 0.f;

  const int tRow = tid >> 4;                    // 0..15
  const int f4 = tid & 15;
  const int swzT = (((f4 >> 1) ^ (tRow & 7)) * 8) + ((f4 & 1) * 4); // ushort units

  int bOff[4], dOff[4];
  #pragma unroll
  for (int k = 0; k < 4; ++k) {
    const int s = k * 256 + tid;
    const int r = s >> 3, c = s & 7;
    bOff[k] = (int)((nblk * 128 + r) * 1024 + ((c ^ (r & 7)) * 8));
    dOff[k] = s * 8;
  }
  ushort_t* const aL = &Ab[0][0];
  ushort_t* const bL = &Bb[0][0];

  int aRow[4], bRow[4];
  #pragma unroll
  for (int m = 0; m < 4; ++m) aRow[m] = (wr * 64 + m * 16 + l15) * 64;
  #pragma unroll
  for (int n = 0; n < 4; ++n) bRow[n] = (wc * 64 + n * 16 + l15) * 64;
  const int ch0 = (q ^ r7) * 8;
  const int ch1 = ((4 + q) ^ r7) * 8;

  f32x4 acc[4][4];
  #pragma unroll
  for (int m = 0; m < 4; ++m)
    #pragma unroll
    for (int n = 0; n < 4; ++n) { f32x4 z = {0.f,0.f,0.f,0.f}; acc[m][n] = z; }

  for (int kt = 0; kt < 16; ++kt) {
    const int ko = kt * 64;
    // B: async LDS-DMA (safe: all waves passed the closing barrier)
    #pragma unroll
    for (int k = 0; k < 4; ++k)
      gload_lds16(WcBf + ko + bOff[k], bL + dOff[k]);

    // A: 8 coalesced float4 loads (16 lanes x 256B contiguous per row)
    float4 av[8];
    #pragma unroll
    for (int k = 0; k < 8; ++k)
      av[k] = encF4[(rowBase + k * 16 + tRow) * 256 + kt * 16 + f4];

    // convert -> swizzled LDS write; nblk==0 also persists bf16 to encBf
    #pragma unroll
    for (int k = 0; k < 8; ++k) {
      uint2 w;
      w.x = pk2bf(av[k].x, av[k].y);
      w.y = pk2bf(av[k].z, av[k].w);
      const int r = k * 16 + tRow;
      *(uint2*)(aL + r * 64 + swzT) = w;
      if (nblk == 0)
        *(uint2*)(encBf + (rowBase + r) * 1024 + ko + f4 * 4) = w;
    }
    __syncthreads();   // drains B vmcnt + A lgkm: both tiles ready

    #pragma unroll
    for (int kk = 0; kk < 2; ++kk) {
      const int cho = kk ? ch1 : ch0;
      bf16x8 af[4], bv[4];
      #pragma unroll
      for (int m = 0; m < 4; ++m) af[m] = *(const bf16x8*)(aL + aRow[m] + cho);
      #pragma unroll
      for (int n = 0; n < 4; ++n) bv[n] = *(const bf16x8*)(bL + bRow[n] + cho);
      #pragma unroll
      for (int m = 0; m < 4; ++m)
        #pragma unroll
        for (int n = 0; n < 4; ++n)
          acc[m][n] = __builtin_amdgcn_mfma_f32_16x16x32_bf16(
              af[m], bv[n], acc[m][n], 0, 0, 0);
    }
    __syncthreads();   // compute done before next iter overwrites tiles
  }

  #pragma unroll
  for (int m = 0; m < 4; ++m) {
    #pragma unroll
    for (int i = 0; i < 4; ++i) {
      const int rowl = wr * 64 + m * 16 + q * 4 + i;
      const int bb2 = rowl & 31;                // global row %32 == rowl%32
      float v = 0.f;
      #pragma unroll
      for (int n = 0; n < 4; ++n) {
        const int col = nblk * 128 + wc * 64 + n * 16 + l15;
        float x = acc[m][n][i] + wsum[bb2 * 1024 + col];
        v += fast_tanh(x) * Wa[col];
      }
      v += __shfl_xor(v, 1); v += __shfl_xor(v, 2);
      v += __shfl_xor(v, 4); v += __shfl_xor(v, 8);
      if (l15 == 0) atomicAdd(&scorep[rowl], v);
    }
  }
  __syncthreads();
  if (tid < 128) {
    const int grow = (int)rowBase + tid;
    const int b = grow & 31, s = grow >> 5;
    scoreP8T[((b * 2048 + s) << 3) + nblk] = scorep[tid];
  }
}

// ---------------------------------------------------------------------------
// ctx (fused partial + last-block reduce): block (b, sc).
// Phase A: exp own 64 s, wave-reduce exp-sum -> gSum[sc*32+b]; accumulate
//   partial[sc][b][e] with plain float4 stores (no atomics).
// Phase B: thread0: __threadfence (device-scope release, wbl2) + counter
//   bump; the 32nd arriver for this b __threadfence's (acquire, invalidates
//   stale L2 incl. prior graph replay) and reduces b's 32 partials + sums,
//   writing out directly. Deterministic: fixed reduction order regardless of
//   which block reduces.
// ---------------------------------------------------------------------------
__global__ __launch_bounds__(256) void ctx_kernel(
    const ushort_t* __restrict__ encBf, const float* __restrict__ scoreP8T,
    float* __restrict__ partial, float* __restrict__ gSum,
    unsigned int* __restrict__ counters, float* __restrict__ out)
{
  const int b = blockIdx.x & 31, sc = blockIdx.x >> 5;
  const int t = threadIdx.x;
  __shared__ float eCh[64];
  __shared__ unsigned int isLast;

  const int chunk0 = sc * 64;
  if (t < 64) {
    const float4* p = (const float4*)(scoreP8T +
                        (((size_t)b * 2048 + chunk0 + t) << 3));
    float4 u = p[0], v = p[1];
    float scv = ((u.x + u.y) + (u.z + u.w)) + ((v.x + v.y) + (v.z + v.w));
    float e = __expf(scv);                      // scores O(1): no max needed
    eCh[t] = e;
    float sum = e;
    sum += __shfl_xor(sum, 1);  sum += __shfl_xor(sum, 2);
    sum += __shfl_xor(sum, 4);  sum += __shfl_xor(sum, 8);
    sum += __shfl_xor(sum, 16); sum += __shfl_xor(sum, 32);
    if (t == 0) gSum[sc * 32 + b] = sum;
  }
  __syncthreads();

  float a0 = 0.f, a1 = 0.f, a2 = 0.f, a3 = 0.f;
  const int e0 = t * 4;
  #pragma unroll 4
  for (int si = 0; si < 64; ++si) {
    const int s = chunk0 + si;
    const float a = eCh[si];
    uint2 w = *(const uint2*)(encBf + ((size_t)s * 32 + b) * 1024 + e0);
    a0 += a * bflo(w.x); a1 += a * bfhi(w.x);
    a2 += a * bflo(w.y); a3 += a * bfhi(w.y);
  }
  *(float4*)(partial + ((size_t)(sc * 32 + b)) * 1024 + e0) =
      make_float4(a0, a1, a2, a3);

  // arrival protocol
  __syncthreads();                       // all waves' stores drained (vmcnt 0)
  if (t == 0) {
    __threadfence();                     // device-scope release (L2 writeback)
    unsigned int old = atomicAdd(&counters[b], 1u);
    isLast = (old == 31u);
  }
  __syncthreads();
  if (!isLast) return;

  __threadfence();                       // acquire: invalidate stale L2 lines
  float tot = 0.f;
  #pragma unroll
  for (int s2 = 0; s2 < 32; ++s2) tot += gSum[s2 * 32 + b];
  const float inv = 1.0f / tot;

  float4 acc = make_float4(0.f, 0.f, 0.f, 0.f);
  #pragma unroll
  for (int s2 = 0; s2 < 32; ++s2) {
    float4 v = *(const float4*)(partial + ((size_t)(s2 * 32 + b)) * 1024 + e0);
    acc.x += v.x; acc.y += v.y; acc.z += v.z; acc.w += v.w;
  }
  acc.x *= inv; acc.y *= inv; acc.z *= inv; acc.w *= inv;
  *(float4*)(out + (size_t)b * 1024 + e0) = acc;
}

// ---------------------------------------------------------------------------
extern "C" void kernel_launch(void* const* d_in, const int* in_sizes, int n_in,
                              void* d_out, int out_size, void* d_ws, size_t ws_size,
                              hipStream_t stream) {
  const float* dec = (const float*)d_in[0];
  const float* enc = (const float*)d_in[1];
  const float* Wb  = (const float*)d_in[2];
  const float* Wc  = (const float*)d_in[3];
  const float* Wa  = (const float*)d_in[4];
  float* out = (float*)d_out;
  (void)in_sizes; (void)n_in; (void)ws_size; (void)out_size;

  char* ws = (char*)d_ws;
  ushort_t* encBf    = (ushort_t*)ws;                                    // 128 MB
  ushort_t* WcBf     = (ushort_t*)(ws + 134217728);                      // 2 MB
  float*    wsum     = (float*)(ws + 134217728 + 2097152);               // 128 KB
  float*    scoreP8T = (float*)(ws + 134217728 + 2097152 + 131072);      // 2 MB
  float*    partial  = (float*)(ws + 134217728 + 2097152 + 131072 + 2097152);        // 4 MB
  float*    gSum     = (float*)(ws + 134217728 + 2097152 + 131072 + 2097152 + 4194304); // 4 KB
  unsigned int* ctr  = (unsigned int*)(ws + 134217728 + 2097152 + 131072 + 2097152 + 4194304 + 4096); // 128 B

  prep_small_kernel<<<96, 256, 0, stream>>>(dec, Wb, Wc, WcBf, wsum, ctr);
  score_kernel<<<4096, 256, 0, stream>>>((const float4*)enc, encBf, WcBf,
                                         wsum, Wa, scoreP8T);
  ctx_kernel<<<1024, 256, 0, stream>>>(encBf, scoreP8T, partial, gSum, ctr, out);
}

// Round 18
// 367.764 us; speedup vs baseline: 1.4587x; 1.0853x over previous
//
#include <hip/hip_runtime.h>
#include <hip/hip_bf16.h>
#include <stdint.h>

// Problem constants
#define S_LEN 2048
#define BATCH 32
#define MROWS (S_LEN*BATCH)   // 65536 GEMM rows, K=N=1024

typedef __attribute__((ext_vector_type(8))) short bf16x8;
typedef __attribute__((ext_vector_type(4))) float f32x4;
typedef unsigned short ushort_t;

__device__ inline unsigned int pk2bf(float a, float b) {
  float2 t; t.x = a; t.y = b;
  __hip_bfloat162 h = __float22bfloat162_rn(t);
  union { __hip_bfloat162 h; unsigned int u; } c; c.h = h;
  return c.u;
}

__device__ inline float bflo(unsigned int u) { return __uint_as_float(u << 16); }
__device__ inline float bfhi(unsigned int u) { return __uint_as_float(u & 0xffff0000u); }

__device__ inline void gload_lds16(const void* g, void* l) {
  __builtin_amdgcn_global_load_lds(
      (const __attribute__((address_space(1))) unsigned int*)g,
      (__attribute__((address_space(3))) unsigned int*)l, 16, 0, 0);
}

__device__ inline float fast_tanh(float x) {
  float e = __expf(2.0f * x);
  return 1.0f - 2.0f / (e + 1.0f);
}

// ---------------------------------------------------------------------------
// prep_small: blocks 0..63 convert Wc -> bf16;
//             blocks 64..95 compute wsum[b][n] = sum_d dec[b][d]*Wb[n][d]
// ---------------------------------------------------------------------------
__global__ __launch_bounds__(256) void prep_small_kernel(
    const float* __restrict__ dec, const float* __restrict__ Wb,
    const float* __restrict__ Wc, ushort_t* __restrict__ WcBf,
    float* __restrict__ wsum)
{
  const int t = threadIdx.x;
  const int bid = blockIdx.x;
  if (bid < 64) {
    const int base = bid * 16384;
    for (int i = 0; i < 16; ++i) {
      int idx = base + i * 1024 + t * 4;
      float4 v = *(const float4*)(Wc + idx);
      uint2 w; w.x = pk2bf(v.x, v.y); w.y = pk2bf(v.z, v.w);
      *(uint2*)(WcBf + idx) = w;
    }
  } else {
    const int j = bid - 64;                     // n-slice [j*32, j*32+32)
    __shared__ float sdec[32][65];
    __shared__ float swb[32][65];
    const int b = t & 31, nl = t >> 5;
    float acc0 = 0.f, acc1 = 0.f, acc2 = 0.f, acc3 = 0.f;
    for (int c = 0; c < 16; ++c) {
      __syncthreads();
      for (int idx = t; idx < 2048; idx += 256) {
        int rr = idx >> 6, dd = idx & 63;
        sdec[rr][dd] = dec[rr * 1024 + c * 64 + dd];
        swb[rr][dd]  = Wb[(size_t)(j * 32 + rr) * 1024 + c * 64 + dd];
      }
      __syncthreads();
      #pragma unroll 8
      for (int dd = 0; dd < 64; ++dd) {
        float dv = sdec[b][dd];
        acc0 += dv * swb[nl][dd];
        acc1 += dv * swb[nl + 8][dd];
        acc2 += dv * swb[nl + 16][dd];
        acc3 += dv * swb[nl + 24][dd];
      }
    }
    wsum[b * 1024 + j * 32 + nl]      = acc0;
    wsum[b * 1024 + j * 32 + nl + 8]  = acc1;
    wsum[b * 1024 + j * 32 + nl + 16] = acc2;
    wsum[b * 1024 + j * 32 + nl + 24] = acc3;
  }
}

// ---------------------------------------------------------------------------
// score (fused m97 structure — session optimum): BM=128, BN=128, BK=64,
// 4 waves (2x2), wave 64x64. Single-buffered 32KB LDS, 2 barriers/K-step,
// 32 MFMA between barriers; latency hidden by 4 blocks/CU wave-level TLP
// (m114), NOT source pipelining (R3/R4/R9/R16 all regressed).
// A: fp32 enc -> regs -> bf16 -> swizzled ds_write (conversion fused, no
//    separate 384MB conv pass); nblk==0 blocks persist bf16 tile to encBf.
// B: bf16 WcBf via async gload_lds w/ pre-swizzled source.
// XOR-8 chunk swizzle on both operands -> conflict-free frag reads.
// XCD-aware bid decode: 8 blocks sharing an A-panel -> same XCD L2.
// Epilogue: scoreP8T[b][s][nblk] = sum_col tanh(acc + wsum) * Wa.
// ---------------------------------------------------------------------------
__global__ __launch_bounds__(256, 4) void score_kernel(
    const float4* __restrict__ encF4, ushort_t* __restrict__ encBf,
    const ushort_t* __restrict__ WcBf, const float* __restrict__ wsum,
    const float* __restrict__ Wa, float* __restrict__ scoreP8T)
{
  __shared__ ushort_t Ab[128][64];   // 16 KB
  __shared__ ushort_t Bb[128][64];   // 16 KB
  __shared__ float scorep[128];

  const int tid = threadIdx.x;
  const int lane = tid & 63;
  const int l15 = lane & 15, q = lane >> 4;
  const int r7 = l15 & 7;
  const int wid = tid >> 6;
  const int wr = wid >> 1, wc = wid & 1;        // 2M x 2N waves
  const int bid = blockIdx.x;
  const int mi = bid & 15, nblk = (bid >> 4) & 7, mg = bid >> 7;
  const size_t rowBase = (size_t)(mg * 16 + mi) * 128;

  if (tid < 128) scorep[tid] = 0.f;

  const int tRow = tid >> 4;                    // 0..15
  const int f4 = tid & 15;
  const int swzT = (((f4 >> 1) ^ (tRow & 7)) * 8) + ((f4 & 1) * 4); // ushort units

  int bOff[4], dOff[4];
  #pragma unroll
  for (int k = 0; k < 4; ++k) {
    const int s = k * 256 + tid;
    const int r = s >> 3, c = s & 7;
    bOff[k] = (int)((nblk * 128 + r) * 1024 + ((c ^ (r & 7)) * 8));
    dOff[k] = s * 8;
  }
  ushort_t* const aL = &Ab[0][0];
  ushort_t* const bL = &Bb[0][0];

  int aRow[4], bRow[4];
  #pragma unroll
  for (int m = 0; m < 4; ++m) aRow[m] = (wr * 64 + m * 16 + l15) * 64;
  #pragma unroll
  for (int n = 0; n < 4; ++n) bRow[n] = (wc * 64 + n * 16 + l15) * 64;
  const int ch0 = (q ^ r7) * 8;
  const int ch1 = ((4 + q) ^ r7) * 8;

  f32x4 acc[4][4];
  #pragma unroll
  for (int m = 0; m < 4; ++m)
    #pragma unroll
    for (int n = 0; n < 4; ++n) { f32x4 z = {0.f,0.f,0.f,0.f}; acc[m][n] = z; }

  for (int kt = 0; kt < 16; ++kt) {
    const int ko = kt * 64;
    // B: async LDS-DMA (safe: all waves passed the closing barrier)
    #pragma unroll
    for (int k = 0; k < 4; ++k)
      gload_lds16(WcBf + ko + bOff[k], bL + dOff[k]);

    // A: 8 coalesced float4 loads (16 lanes x 256B contiguous per row)
    float4 av[8];
    #pragma unroll
    for (int k = 0; k < 8; ++k)
      av[k] = encF4[(rowBase + k * 16 + tRow) * 256 + kt * 16 + f4];

    // convert -> swizzled LDS write; nblk==0 also persists bf16 to encBf
    #pragma unroll
    for (int k = 0; k < 8; ++k) {
      uint2 w;
      w.x = pk2bf(av[k].x, av[k].y);
      w.y = pk2bf(av[k].z, av[k].w);
      const int r = k * 16 + tRow;
      *(uint2*)(aL + r * 64 + swzT) = w;
      if (nblk == 0)
        *(uint2*)(encBf + (rowBase + r) * 1024 + ko + f4 * 4) = w;
    }
    __syncthreads();   // drains B vmcnt + A lgkm: both tiles ready

    #pragma unroll
    for (int kk = 0; kk < 2; ++kk) {
      const int cho = kk ? ch1 : ch0;
      bf16x8 af[4], bv[4];
      #pragma unroll
      for (int m = 0; m < 4; ++m) af[m] = *(const bf16x8*)(aL + aRow[m] + cho);
      #pragma unroll
      for (int n = 0; n < 4; ++n) bv[n] = *(const bf16x8*)(bL + bRow[n] + cho);
      #pragma unroll
      for (int m = 0; m < 4; ++m)
        #pragma unroll
        for (int n = 0; n < 4; ++n)
          acc[m][n] = __builtin_amdgcn_mfma_f32_16x16x32_bf16(
              af[m], bv[n], acc[m][n], 0, 0, 0);
    }
    __syncthreads();   // compute done before next iter overwrites tiles
  }

  #pragma unroll
  for (int m = 0; m < 4; ++m) {
    #pragma unroll
    for (int i = 0; i < 4; ++i) {
      const int rowl = wr * 64 + m * 16 + q * 4 + i;
      const int bb2 = rowl & 31;                // global row %32 == rowl%32
      float v = 0.f;
      #pragma unroll
      for (int n = 0; n < 4; ++n) {
        const int col = nblk * 128 + wc * 64 + n * 16 + l15;
        float x = acc[m][n][i] + wsum[bb2 * 1024 + col];
        v += fast_tanh(x) * Wa[col];
      }
      v += __shfl_xor(v, 1); v += __shfl_xor(v, 2);
      v += __shfl_xor(v, 4); v += __shfl_xor(v, 8);
      if (l15 == 0) atomicAdd(&scorep[rowl], v);
    }
  }
  __syncthreads();
  if (tid < 128) {
    const int grow = (int)rowBase + tid;
    const int b = grow & 31, s = grow >> 5;
    scoreP8T[((b * 2048 + s) << 3) + nblk] = scorep[tid];
  }
}

// ---------------------------------------------------------------------------
// ctx_partial (deterministic, NO global atomics): block (b, sc).
// Exp only for own 64 s (normalization deferred); wave-reduce chunk exp-sum
// -> gSum[sc*32+b]; accumulate partial[sc][b][e] with plain float4 stores.
// ---------------------------------------------------------------------------
__global__ __launch_bounds__(256) void ctx_partial_kernel(
    const ushort_t* __restrict__ encBf, const float* __restrict__ scoreP8T,
    float* __restrict__ partial, float* __restrict__ gSum)
{
  const int b = blockIdx.x & 31, sc = blockIdx.x >> 5;
  const int t = threadIdx.x;
  __shared__ float eCh[64];

  const int chunk0 = sc * 64;
  if (t < 64) {
    const float4* p = (const float4*)(scoreP8T +
                        (((size_t)b * 2048 + chunk0 + t) << 3));
    float4 u = p[0], v = p[1];
    float scv = ((u.x + u.y) + (u.z + u.w)) + ((v.x + v.y) + (v.z + v.w));
    float e = __expf(scv);                      // scores O(1): no max needed
    eCh[t] = e;
    float sum = e;
    sum += __shfl_xor(sum, 1);  sum += __shfl_xor(sum, 2);
    sum += __shfl_xor(sum, 4);  sum += __shfl_xor(sum, 8);
    sum += __shfl_xor(sum, 16); sum += __shfl_xor(sum, 32);
    if (t == 0) gSum[sc * 32 + b] = sum;
  }
  __syncthreads();

  float a0 = 0.f, a1 = 0.f, a2 = 0.f, a3 = 0.f;
  const int e0 = t * 4;
  #pragma unroll 4
  for (int si = 0; si < 64; ++si) {
    const int s = chunk0 + si;
    const float a = eCh[si];
    uint2 w = *(const uint2*)(encBf + ((size_t)s * 32 + b) * 1024 + e0);
    a0 += a * bflo(w.x); a1 += a * bfhi(w.x);
    a2 += a * bflo(w.y); a3 += a * bfhi(w.y);
  }
  *(float4*)(partial + ((size_t)(sc * 32 + b)) * 1024 + e0) =
      make_float4(a0, a1, a2, a3);
}

// ---------------------------------------------------------------------------
// ctx_reduce: block b. Sum 32 chunk partials + 32 chunk exp-sums, scale by
// 1/total, write out directly (no pre-zeroing needed anywhere).
// ---------------------------------------------------------------------------
__global__ __launch_bounds__(256) void ctx_reduce_kernel(
    const float* __restrict__ partial, const float* __restrict__ gSum,
    float* __restrict__ out)
{
  const int b = blockIdx.x, t = threadIdx.x;
  float tot = 0.f;
  #pragma unroll
  for (int sc = 0; sc < 32; ++sc) tot += gSum[sc * 32 + b];
  const float inv = 1.0f / tot;

  float4 acc = make_float4(0.f, 0.f, 0.f, 0.f);
  #pragma unroll
  for (int sc = 0; sc < 32; ++sc) {
    float4 v = *(const float4*)(partial + ((size_t)(sc * 32 + b)) * 1024 + t * 4);
    acc.x += v.x; acc.y += v.y; acc.z += v.z; acc.w += v.w;
  }
  acc.x *= inv; acc.y *= inv; acc.z *= inv; acc.w *= inv;
  *(float4*)(out + (size_t)b * 1024 + t * 4) = acc;
}

// ---------------------------------------------------------------------------
extern "C" void kernel_launch(void* const* d_in, const int* in_sizes, int n_in,
                              void* d_out, int out_size, void* d_ws, size_t ws_size,
                              hipStream_t stream) {
  const float* dec = (const float*)d_in[0];
  const float* enc = (const float*)d_in[1];
  const float* Wb  = (const float*)d_in[2];
  const float* Wc  = (const float*)d_in[3];
  const float* Wa  = (const float*)d_in[4];
  float* out = (float*)d_out;
  (void)in_sizes; (void)n_in; (void)ws_size; (void)out_size;

  char* ws = (char*)d_ws;
  ushort_t* encBf    = (ushort_t*)ws;                                    // 128 MB
  ushort_t* WcBf     = (ushort_t*)(ws + 134217728);                      // 2 MB
  float*    wsum     = (float*)(ws + 134217728 + 2097152);               // 128 KB
  float*    scoreP8T = (float*)(ws + 134217728 + 2097152 + 131072);      // 2 MB
  float*    partial  = (float*)(ws + 134217728 + 2097152 + 131072 + 2097152);        // 4 MB
  float*    gSum     = (float*)(ws + 134217728 + 2097152 + 131072 + 2097152 + 4194304); // 4 KB

  prep_small_kernel<<<96, 256, 0, stream>>>(dec, Wb, Wc, WcBf, wsum);
  score_kernel<<<4096, 256, 0, stream>>>((const float4*)enc, encBf, WcBf,
                                         wsum, Wa, scoreP8T);
  ctx_partial_kernel<<<1024, 256, 0, stream>>>(encBf, scoreP8T, partial, gSum);
  ctx_reduce_kernel<<<32, 256, 0, stream>>>(partial, gSum, out);
}

// Round 19
// 366.380 us; speedup vs baseline: 1.4642x; 1.0038x over previous
//
#include <hip/hip_runtime.h>
#include <hip/hip_bf16.h>
#include <stdint.h>

// Problem constants
#define S_LEN 2048
#define BATCH 32
#define MROWS (S_LEN*BATCH)   // 65536 GEMM rows, K=N=1024

typedef __attribute__((ext_vector_type(8))) short bf16x8;
typedef __attribute__((ext_vector_type(4))) float f32x4;
typedef unsigned short ushort_t;

__device__ inline unsigned int pk2bf(float a, float b) {
  float2 t; t.x = a; t.y = b;
  __hip_bfloat162 h = __float22bfloat162_rn(t);
  union { __hip_bfloat162 h; unsigned int u; } c; c.h = h;
  return c.u;
}

__device__ inline float bflo(unsigned int u) { return __uint_as_float(u << 16); }
__device__ inline float bfhi(unsigned int u) { return __uint_as_float(u & 0xffff0000u); }

__device__ inline void gload_lds16(const void* g, void* l) {
  __builtin_amdgcn_global_load_lds(
      (const __attribute__((address_space(1))) unsigned int*)g,
      (__attribute__((address_space(3))) unsigned int*)l, 16, 0, 0);
}

__device__ inline float fast_tanh(float x) {
  float e = __expf(2.0f * x);
  return 1.0f - 2.0f / (e + 1.0f);
}

// ---------------------------------------------------------------------------
// prep_small: blocks 0..255 convert Wc -> bf16 (slim blocks: 4 iters each,
//             4x the parallelism of the old 64-block version);
//             blocks 256..287 compute wsum[b][n] = sum_d dec[b][d]*Wb[n][d]
// ---------------------------------------------------------------------------
__global__ __launch_bounds__(256) void prep_small_kernel(
    const float* __restrict__ dec, const float* __restrict__ Wb,
    const float* __restrict__ Wc, ushort_t* __restrict__ WcBf,
    float* __restrict__ wsum)
{
  const int t = threadIdx.x;
  const int bid = blockIdx.x;
  if (bid < 256) {
    const int base = bid * 4096;
    #pragma unroll
    for (int i = 0; i < 4; ++i) {
      int idx = base + i * 1024 + t * 4;
      float4 v = *(const float4*)(Wc + idx);
      uint2 w; w.x = pk2bf(v.x, v.y); w.y = pk2bf(v.z, v.w);
      *(uint2*)(WcBf + idx) = w;
    }
  } else {
    const int j = bid - 256;                    // n-slice [j*32, j*32+32)
    __shared__ float sdec[32][65];
    __shared__ float swb[32][65];
    const int b = t & 31, nl = t >> 5;
    float acc0 = 0.f, acc1 = 0.f, acc2 = 0.f, acc3 = 0.f;
    for (int c = 0; c < 16; ++c) {
      __syncthreads();
      for (int idx = t; idx < 2048; idx += 256) {
        int rr = idx >> 6, dd = idx & 63;
        sdec[rr][dd] = dec[rr * 1024 + c * 64 + dd];
        swb[rr][dd]  = Wb[(size_t)(j * 32 + rr) * 1024 + c * 64 + dd];
      }
      __syncthreads();
      #pragma unroll 8
      for (int dd = 0; dd < 64; ++dd) {
        float dv = sdec[b][dd];
        acc0 += dv * swb[nl][dd];
        acc1 += dv * swb[nl + 8][dd];
        acc2 += dv * swb[nl + 16][dd];
        acc3 += dv * swb[nl + 24][dd];
      }
    }
    wsum[b * 1024 + j * 32 + nl]      = acc0;
    wsum[b * 1024 + j * 32 + nl + 8]  = acc1;
    wsum[b * 1024 + j * 32 + nl + 16] = acc2;
    wsum[b * 1024 + j * 32 + nl + 24] = acc3;
  }
}

// ---------------------------------------------------------------------------
// score (fused m97 structure — session optimum, byte-identical to R15/R18):
// BM=128, BN=128, BK=64, 4 waves (2x2), wave 64x64. Single-buffered 32KB
// LDS, 2 barriers/K-step, 32 MFMA between barriers; latency hidden by
// 4 blocks/CU wave-level TLP (m114), NOT source pipelining (R3/R4/R9/R16
// all regressed).
// A: fp32 enc -> regs -> bf16 -> swizzled ds_write (conversion fused, no
//    separate 384MB conv pass); nblk==0 blocks persist bf16 tile to encBf.
// B: bf16 WcBf via async gload_lds w/ pre-swizzled source.
// XOR-8 chunk swizzle on both operands -> conflict-free frag reads.
// XCD-aware bid decode: 8 blocks sharing an A-panel -> same XCD L2.
// Epilogue: scoreP8T[b][s][nblk] = sum_col tanh(acc + wsum) * Wa.
// ---------------------------------------------------------------------------
__global__ __launch_bounds__(256, 4) void score_kernel(
    const float4* __restrict__ encF4, ushort_t* __restrict__ encBf,
    const ushort_t* __restrict__ WcBf, const float* __restrict__ wsum,
    const float* __restrict__ Wa, float* __restrict__ scoreP8T)
{
  __shared__ ushort_t Ab[128][64];   // 16 KB
  __shared__ ushort_t Bb[128][64];   // 16 KB
  __shared__ float scorep[128];

  const int tid = threadIdx.x;
  const int lane = tid & 63;
  const int l15 = lane & 15, q = lane >> 4;
  const int r7 = l15 & 7;
  const int wid = tid >> 6;
  const int wr = wid >> 1, wc = wid & 1;        // 2M x 2N waves
  const int bid = blockIdx.x;
  const int mi = bid & 15, nblk = (bid >> 4) & 7, mg = bid >> 7;
  const size_t rowBase = (size_t)(mg * 16 + mi) * 128;

  if (tid < 128) scorep[tid] = 0.f;

  const int tRow = tid >> 4;                    // 0..15
  const int f4 = tid & 15;
  const int swzT = (((f4 >> 1) ^ (tRow & 7)) * 8) + ((f4 & 1) * 4); // ushort units

  int bOff[4], dOff[4];
  #pragma unroll
  for (int k = 0; k < 4; ++k) {
    const int s = k * 256 + tid;
    const int r = s >> 3, c = s & 7;
    bOff[k] = (int)((nblk * 128 + r) * 1024 + ((c ^ (r & 7)) * 8));
    dOff[k] = s * 8;
  }
  ushort_t* const aL = &Ab[0][0];
  ushort_t* const bL = &Bb[0][0];

  int aRow[4], bRow[4];
  #pragma unroll
  for (int m = 0; m < 4; ++m) aRow[m] = (wr * 64 + m * 16 + l15) * 64;
  #pragma unroll
  for (int n = 0; n < 4; ++n) bRow[n] = (wc * 64 + n * 16 + l15) * 64;
  const int ch0 = (q ^ r7) * 8;
  const int ch1 = ((4 + q) ^ r7) * 8;

  f32x4 acc[4][4];
  #pragma unroll
  for (int m = 0; m < 4; ++m)
    #pragma unroll
    for (int n = 0; n < 4; ++n) { f32x4 z = {0.f,0.f,0.f,0.f}; acc[m][n] = z; }

  for (int kt = 0; kt < 16; ++kt) {
    const int ko = kt * 64;
    // B: async LDS-DMA (safe: all waves passed the closing barrier)
    #pragma unroll
    for (int k = 0; k < 4; ++k)
      gload_lds16(WcBf + ko + bOff[k], bL + dOff[k]);

    // A: 8 coalesced float4 loads (16 lanes x 256B contiguous per row)
    float4 av[8];
    #pragma unroll
    for (int k = 0; k < 8; ++k)
      av[k] = encF4[(rowBase + k * 16 + tRow) * 256 + kt * 16 + f4];

    // convert -> swizzled LDS write; nblk==0 also persists bf16 to encBf
    #pragma unroll
    for (int k = 0; k < 8; ++k) {
      uint2 w;
      w.x = pk2bf(av[k].x, av[k].y);
      w.y = pk2bf(av[k].z, av[k].w);
      const int r = k * 16 + tRow;
      *(uint2*)(aL + r * 64 + swzT) = w;
      if (nblk == 0)
        *(uint2*)(encBf + (rowBase + r) * 1024 + ko + f4 * 4) = w;
    }
    __syncthreads();   // drains B vmcnt + A lgkm: both tiles ready

    #pragma unroll
    for (int kk = 0; kk < 2; ++kk) {
      const int cho = kk ? ch1 : ch0;
      bf16x8 af[4], bv[4];
      #pragma unroll
      for (int m = 0; m < 4; ++m) af[m] = *(const bf16x8*)(aL + aRow[m] + cho);
      #pragma unroll
      for (int n = 0; n < 4; ++n) bv[n] = *(const bf16x8*)(bL + bRow[n] + cho);
      #pragma unroll
      for (int m = 0; m < 4; ++m)
        #pragma unroll
        for (int n = 0; n < 4; ++n)
          acc[m][n] = __builtin_amdgcn_mfma_f32_16x16x32_bf16(
              af[m], bv[n], acc[m][n], 0, 0, 0);
    }
    __syncthreads();   // compute done before next iter overwrites tiles
  }

  #pragma unroll
  for (int m = 0; m < 4; ++m) {
    #pragma unroll
    for (int i = 0; i < 4; ++i) {
      const int rowl = wr * 64 + m * 16 + q * 4 + i;
      const int bb2 = rowl & 31;                // global row %32 == rowl%32
      float v = 0.f;
      #pragma unroll
      for (int n = 0; n < 4; ++n) {
        const int col = nblk * 128 + wc * 64 + n * 16 + l15;
        float x = acc[m][n][i] + wsum[bb2 * 1024 + col];
        v += fast_tanh(x) * Wa[col];
      }
      v += __shfl_xor(v, 1); v += __shfl_xor(v, 2);
      v += __shfl_xor(v, 4); v += __shfl_xor(v, 8);
      if (l15 == 0) atomicAdd(&scorep[rowl], v);
    }
  }
  __syncthreads();
  if (tid < 128) {
    const int grow = (int)rowBase + tid;
    const int b = grow & 31, s = grow >> 5;
    scoreP8T[((b * 2048 + s) << 3) + nblk] = scorep[tid];
  }
}

// ---------------------------------------------------------------------------
// ctx_partial (deterministic, NO global atomics): block (b, sc).
// Exp only for own 64 s (normalization deferred); wave-reduce chunk exp-sum
// -> gSum[sc*32+b]; accumulate partial[sc][b][e] with plain float4 stores.
// ---------------------------------------------------------------------------
__global__ __launch_bounds__(256) void ctx_partial_kernel(
    const ushort_t* __restrict__ encBf, const float* __restrict__ scoreP8T,
    float* __restrict__ partial, float* __restrict__ gSum)
{
  const int b = blockIdx.x & 31, sc = blockIdx.x >> 5;
  const int t = threadIdx.x;
  __shared__ float eCh[64];

  const int chunk0 = sc * 64;
  if (t < 64) {
    const float4* p = (const float4*)(scoreP8T +
                        (((size_t)b * 2048 + chunk0 + t) << 3));
    float4 u = p[0], v = p[1];
    float scv = ((u.x + u.y) + (u.z + u.w)) + ((v.x + v.y) + (v.z + v.w));
    float e = __expf(scv);                      // scores O(1): no max needed
    eCh[t] = e;
    float sum = e;
    sum += __shfl_xor(sum, 1);  sum += __shfl_xor(sum, 2);
    sum += __shfl_xor(sum, 4);  sum += __shfl_xor(sum, 8);
    sum += __shfl_xor(sum, 16); sum += __shfl_xor(sum, 32);
    if (t == 0) gSum[sc * 32 + b] = sum;
  }
  __syncthreads();

  float a0 = 0.f, a1 = 0.f, a2 = 0.f, a3 = 0.f;
  const int e0 = t * 4;
  #pragma unroll 8
  for (int si = 0; si < 64; ++si) {
    const int s = chunk0 + si;
    const float a = eCh[si];
    uint2 w = *(const uint2*)(encBf + ((size_t)s * 32 + b) * 1024 + e0);
    a0 += a * bflo(w.x); a1 += a * bfhi(w.x);
    a2 += a * bflo(w.y); a3 += a * bfhi(w.y);
  }
  *(float4*)(partial + ((size_t)(sc * 32 + b)) * 1024 + e0) =
      make_float4(a0, a1, a2, a3);
}

// ---------------------------------------------------------------------------
// ctx_reduce: block b. Sum 32 chunk partials + 32 chunk exp-sums, scale by
// 1/total, write out directly (no pre-zeroing needed anywhere).
// ---------------------------------------------------------------------------
__global__ __launch_bounds__(256) void ctx_reduce_kernel(
    const float* __restrict__ partial, const float* __restrict__ gSum,
    float* __restrict__ out)
{
  const int b = blockIdx.x, t = threadIdx.x;
  float tot = 0.f;
  #pragma unroll
  for (int sc = 0; sc < 32; ++sc) tot += gSum[sc * 32 + b];
  const float inv = 1.0f / tot;

  float4 acc = make_float4(0.f, 0.f, 0.f, 0.f);
  #pragma unroll
  for (int sc = 0; sc < 32; ++sc) {
    float4 v = *(const float4*)(partial + ((size_t)(sc * 32 + b)) * 1024 + t * 4);
    acc.x += v.x; acc.y += v.y; acc.z += v.z; acc.w += v.w;
  }
  acc.x *= inv; acc.y *= inv; acc.z *= inv; acc.w *= inv;
  *(float4*)(out + (size_t)b * 1024 + t * 4) = acc;
}

// ---------------------------------------------------------------------------
extern "C" void kernel_launch(void* const* d_in, const int* in_sizes, int n_in,
                              void* d_out, int out_size, void* d_ws, size_t ws_size,
                              hipStream_t stream) {
  const float* dec = (const float*)d_in[0];
  const float* enc = (const float*)d_in[1];
  const float* Wb  = (const float*)d_in[2];
  const float* Wc  = (const float*)d_in[3];
  const float* Wa  = (const float*)d_in[4];
  float* out = (float*)d_out;
  (void)in_sizes; (void)n_in; (void)ws_size; (void)out_size;

  char* ws = (char*)d_ws;
  ushort_t* encBf    = (ushort_t*)ws;                                    // 128 MB
  ushort_t* WcBf     = (ushort_t*)(ws + 134217728);                      // 2 MB
  float*    wsum     = (float*)(ws + 134217728 + 2097152);               // 128 KB
  float*    scoreP8T = (float*)(ws + 134217728 + 2097152 + 131072);      // 2 MB
  float*    partial  = (float*)(ws + 134217728 + 2097152 + 131072 + 2097152);        // 4 MB
  float*    gSum     = (float*)(ws + 134217728 + 2097152 + 131072 + 2097152 + 4194304); // 4 KB

  prep_small_kernel<<<288, 256, 0, stream>>>(dec, Wb, Wc, WcBf, wsum);
  score_kernel<<<4096, 256, 0, stream>>>((const float4*)enc, encBf, WcBf,
                                         wsum, Wa, scoreP8T);
  ctx_partial_kernel<<<1024, 256, 0, stream>>>(encBf, scoreP8T, partial, gSum);
  ctx_reduce_kernel<<<32, 256, 0, stream>>>(partial, gSum, out);
}